// Round 4
// baseline (204.198 us; speedup 1.0000x reference)
//
#include <hip/hip_runtime.h>
#include <math.h>

#define H 256
#define COLSN 64
#define ROWSN 200000
#define T_STEPS 4
#define QLEN 40
#define NNUM 5
#define NOPS 9

// workspace float offsets
#define WS_XWB    0          // 40*256 : X@Wx + b
#define WS_AOP    10240      // 4*16
#define WS_ACOL   10304      // 4*64
#define WS_PIV    10560      // [0]=g_pivot [1]=l_pivot
#define WS_ACC    10568      // dot[4], cnt[4]
#define WS_TICKET 10576      // block completion ticket
#define WS_MOP    10752      // 9*256  : M_op[k][i]  = op_emb[k] . W_hc[i][:256]
#define WS_MCOL   13056      // 64*256 : M_col[c][i] = col_emb[c] . W_hc[i][256:]

#define NTBL_BLOCKS 782

// DPP-based partial-sum add (VALU pipe)
template<int CTRL>
__device__ __forceinline__ float dpp_add(float x) {
    int xi = __float_as_int(x);
    int yi = __builtin_amdgcn_update_dpp(0, xi, CTRL, 0xF, 0xF, true);
    return x + __int_as_float(yi);
}
#define DPP_XOR1 0xB1   // quad_perm [1,0,3,2]  (lane^1)
#define DPP_XOR2 0x4E   // quad_perm [2,3,0,1]  (lane^2)
#define DPP_HMIR 0x141  // row_half_mirror      (lane^7)
#define DPP_MIR  0x140  // row_mirror           (lane^15)

// 16-lane-group sum, result in all lanes of the group
__device__ __forceinline__ float reduce16(float v) {
    v = dpp_add<DPP_XOR1>(v);
    v = dpp_add<DPP_XOR2>(v);
    v = dpp_add<DPP_HMIR>(v);
    v = dpp_add<DPP_MIR>(v);
    return v;
}

__device__ __forceinline__ float fast_tanh(float x) {
    float cx = fminf(15.f, fmaxf(-15.f, x));
    float e = __expf(2.f * cx);
    return __fdividef(e - 1.f, e + 1.f);
}

__device__ __forceinline__ float dot4(float4 a, float4 b) {
    return a.x * b.x + a.y * b.y + a.z * b.z + a.w * b.w;
}

// LDS swizzle: +4 floats pad per 16 -> stride-20 float4 reads are 2-way (free)
__device__ __forceinline__ int sw(int i) { return i + ((i >> 4) << 2); }

// ==== k_pre: blocks 0..39 -> X@Wx+b ; blocks 40..47 -> M matrices ====
__global__ __launch_bounds__(256) void k_pre(const int* __restrict__ iq,
        const float* __restrict__ E, const float* __restrict__ Wx,
        const float* __restrict__ b, const float* __restrict__ W_hc,
        const float* __restrict__ op_emb, const float* __restrict__ col_emb,
        float* __restrict__ ws) {
    int blk = blockIdx.x;
    int tid = threadIdx.x;
    if (blk < QLEN) {
        if (blk == 0 && tid < 16) ws[WS_ACC + tid] = 0.f;   // ACC[8] + TICKET
        int word = iq[blk];
        const float* erow = E + (long)word * H;
        float acc = b[tid];
        #pragma unroll 8
        for (int j = 0; j < H; ++j) acc += erow[j] * Wx[j * H + tid];
        ws[WS_XWB + blk * H + tid] = acc;
    } else {
        // M_op / M_col for i-tile [bi*32, bi*32+32)
        __shared__ __attribute__((aligned(16))) float tile[32][516];
        int bi = blk - QLEN;          // 0..7
        int ibase = bi * 32;
        const float4* src = (const float4*)(W_hc + (long)ibase * 2 * H);
        for (int idx = tid; idx < 32 * 128; idx += 256) {
            int row = idx >> 7, c4 = idx & 127;
            *(float4*)&tile[row][c4 * 4] = src[idx];
        }
        __syncthreads();
        int l8 = tid & 7;
        int io = tid >> 3;            // 0..31
        for (int k = 0; k < NOPS + COLSN; ++k) {
            const float* emb = (k < NOPS) ? (op_emb + k * H) : (col_emb + (k - NOPS) * H);
            int coff = (k < NOPS) ? 0 : H;
            float s = 0.f;
            const float* ep = emb + l8 * 32;
            const float* tr = &tile[io][coff + l8 * 32];
            #pragma unroll
            for (int ss = 0; ss < 8; ++ss) {
                int q4 = (ss + io) & 7;               // rotation: 2-way LDS banks
                float4 e4 = *(const float4*)&ep[q4 * 4];
                float4 t4 = *(const float4*)&tr[q4 * 4];
                s += dot4(e4, t4);
            }
            s += __shfl_xor(s, 1);
            s += __shfl_xor(s, 2);
            s += __shfl_xor(s, 4);
            if (l8 == 0) {
                int dst = (k < NOPS) ? (WS_MOP + k * H) : (WS_MCOL + (k - NOPS) * H);
                ws[dst + ibase + io] = s;
            }
        }
    }
}

// ==== k_main: question RNN + pivots + selector, one block x 1024 threads ====
__global__ __launch_bounds__(1024) void k_main(
        const float* __restrict__ Wh, const int* __restrict__ lwi,
        const float* __restrict__ U, const float* __restrict__ qn,
        const float* __restrict__ W_op, const float* __restrict__ W_col,
        const float* __restrict__ W_hh, const float* __restrict__ op_emb,
        const float* __restrict__ col_emb, float* __restrict__ ws) {
    __shared__ __attribute__((aligned(16))) float xwb[QLEN][H];   // 40 KB
    __shared__ __attribute__((aligned(16))) float hbuf[2][320];
    __shared__ __attribute__((aligned(16))) float qsw[320];
    __shared__ __attribute__((aligned(16))) float hhsw[320];
    __shared__ __attribute__((aligned(16))) float uopsw[320];
    __shared__ __attribute__((aligned(16))) float ucolsw[320];
    __shared__ float Z[NNUM][H];
    __shared__ float Pop[H], Pcol[H], vhh[H];
    __shared__ float lg[16];
    __shared__ float lgs[80];
    __shared__ float aop_s[16], acol_s[64];

    const int tid = threadIdx.x;      // 1024
    const int g = tid >> 4;           // 0..63
    const int p = tid & 15;           // 0..15
    const int pb = p * 20;            // swizzled float base of slice p

    // RNN weight fragment: w4[jj].{x..w} = Wh[p*16+jj][g*4 .. g*4+3]
    float4 w4[16];
    #pragma unroll
    for (int jj = 0; jj < 16; ++jj)
        w4[jj] = *(const float4*)&Wh[(p * 16 + jj) * H + g * 4];

    // preload X@Wx+b into LDS; zero h buffers
    {
        const float4* src = (const float4*)&ws[WS_XWB];
        float4* dst = (float4*)&xwb[0][0];
        #pragma unroll 4
        for (int idx = tid; idx < QLEN * H / 4; idx += 1024) dst[idx] = src[idx];
    }
    if (tid < 320) { hbuf[0][tid] = 0.f; hbuf[1][tid] = 0.f; hhsw[tid] = 0.f; }
    __syncthreads();

    const int lw0 = lwi[0], lw1 = lwi[1], lw2 = lwi[2], lw3 = lwi[3], lw4 = lwi[4];
    int cur = 0;
    for (int t = 0; t < QLEN; ++t) {
        const float* hb = hbuf[cur];
        float4 h0 = *(const float4*)&hb[pb + 0];
        float4 h1 = *(const float4*)&hb[pb + 4];
        float4 h2 = *(const float4*)&hb[pb + 8];
        float4 h3 = *(const float4*)&hb[pb + 12];
        float a0 = 0.f, a1 = 0.f, a2 = 0.f, a3 = 0.f;
        #define RNN_FMA(hv, e, jj) \
            a0 += hv.e * w4[jj].x; a1 += hv.e * w4[jj].y; \
            a2 += hv.e * w4[jj].z; a3 += hv.e * w4[jj].w;
        RNN_FMA(h0, x, 0)  RNN_FMA(h0, y, 1)  RNN_FMA(h0, z, 2)  RNN_FMA(h0, w, 3)
        RNN_FMA(h1, x, 4)  RNN_FMA(h1, y, 5)  RNN_FMA(h1, z, 6)  RNN_FMA(h1, w, 7)
        RNN_FMA(h2, x, 8)  RNN_FMA(h2, y, 9)  RNN_FMA(h2, z, 10) RNN_FMA(h2, w, 11)
        RNN_FMA(h3, x, 12) RNN_FMA(h3, y, 13) RNN_FMA(h3, z, 14) RNN_FMA(h3, w, 15)
        #undef RNN_FMA
        a0 = reduce16(a0); a1 = reduce16(a1); a2 = reduce16(a2); a3 = reduce16(a3);
        if (p < 4) {
            float s = (p == 0) ? a0 : (p == 1) ? a1 : (p == 2) ? a2 : a3;
            int i = g * 4 + p;
            float hn = fast_tanh(xwb[t][i] + s);
            hbuf[cur ^ 1][sw(i)] = hn;
            if (t == lw0) Z[0][i] = hn;
            if (t == lw1) Z[1][i] = hn;
            if (t == lw2) Z[2][i] = hn;
            if (t == lw3) Z[3][i] = hn;
            if (t == lw4) Z[4][i] = hn;
        }
        __syncthreads();
        cur ^= 1;
    }
    // q (already in swizzled form)
    if (tid < 320) qsw[tid] = hbuf[cur][tid];

    // pivot logits: 10 dots of 256
    {
        int grp = tid >> 5, lane = tid & 31;
        if (grp < 10) {
            int u = grp / 5, n = grp % 5;
            float s = 0.f;
            #pragma unroll
            for (int k = 0; k < 8; ++k) {
                int j = lane + k * 32;
                s += Z[n][j] * U[u * H + j];
            }
            s += __shfl_xor(s, 1);
            s += __shfl_xor(s, 2);
            s += __shfl_xor(s, 4);
            s += __shfl_xor(s, 8);
            s += __shfl_xor(s, 16);
            if (lane == 0) lg[grp] = s;
        }
    }
    __syncthreads();
    if (tid < 2) {
        float m = -1e30f;
        for (int n = 0; n < 5; ++n) m = fmaxf(m, lg[tid * 5 + n]);
        float e[5], s = 0.f;
        for (int n = 0; n < 5; ++n) { e[n] = expf(lg[tid * 5 + n] - m); s += e[n]; }
        float piv = 0.f;
        for (int n = 0; n < 5; ++n) piv += (e[n] / s) * qn[n];
        ws[WS_PIV + (tid == 0 ? 1 : 0)] = piv;   // PIV[0]=g, PIV[1]=l
    }

    // prologue: P_op / P_col = W[:, :256] @ q  (runs same barrier-epoch as pivots)
    {
        float4 q0 = *(const float4*)&qsw[pb + 0];
        float4 q1 = *(const float4*)&qsw[pb + 4];
        float4 q2 = *(const float4*)&qsw[pb + 8];
        float4 q3 = *(const float4*)&qsw[pb + 12];
        #pragma unroll 2
        for (int k = 0; k < 8; ++k) {
            int o = g + (k << 6);        // 0..511
            const float* row = (o < H) ? &W_op[(long)o * 2 * H + p * 16]
                                       : &W_col[(long)(o - H) * 2 * H + p * 16];
            float4 r0 = *(const float4*)&row[0];
            float4 r1 = *(const float4*)&row[4];
            float4 r2 = *(const float4*)&row[8];
            float4 r3 = *(const float4*)&row[12];
            float s = dot4(r0, q0) + dot4(r1, q1) + dot4(r2, q2) + dot4(r3, q3);
            s = reduce16(s);
            if (p == 0) { if (o < H) Pop[o] = s; else Pcol[o - H] = s; }
        }
    }
    __syncthreads();

    // ---- selector timesteps ----
    for (int t = 0; t < T_STEPS; ++t) {
        // stage A: u_op, u_col, vhh = {W_op2, W_col2, W_hh} @ h
        {
            float4 hh0 = *(const float4*)&hhsw[pb + 0];
            float4 hh1 = *(const float4*)&hhsw[pb + 4];
            float4 hh2 = *(const float4*)&hhsw[pb + 8];
            float4 hh3 = *(const float4*)&hhsw[pb + 12];
            #pragma unroll 2
            for (int k = 0; k < 12; ++k) {
                int o = g + (k << 6);    // 0..767
                const float* row;
                if (o < H)          row = &W_op[(long)o * 2 * H + H + p * 16];
                else if (o < 2 * H) row = &W_col[(long)(o - H) * 2 * H + H + p * 16];
                else                row = &W_hh[(long)(o - 2 * H) * H + p * 16];
                float4 r0 = *(const float4*)&row[0];
                float4 r1 = *(const float4*)&row[4];
                float4 r2 = *(const float4*)&row[8];
                float4 r3 = *(const float4*)&row[12];
                float s = dot4(r0, hh0) + dot4(r1, hh1) + dot4(r2, hh2) + dot4(r3, hh3);
                s = reduce16(s);
                if (p == 0) {
                    if (o < H)          uopsw[sw(o)] = fast_tanh(Pop[o] + s);
                    else if (o < 2 * H) { int oo = o - H; ucolsw[sw(oo)] = fast_tanh(Pcol[oo] + s); }
                    else                vhh[o - 2 * H] = s;
                }
            }
        }
        __syncthreads();
        // logits: 73 dots of 256
        {
            float4 uo0 = *(const float4*)&uopsw[pb + 0];
            float4 uo1 = *(const float4*)&uopsw[pb + 4];
            float4 uo2 = *(const float4*)&uopsw[pb + 8];
            float4 uo3 = *(const float4*)&uopsw[pb + 12];
            float4 uc0 = *(const float4*)&ucolsw[pb + 0];
            float4 uc1 = *(const float4*)&ucolsw[pb + 4];
            float4 uc2 = *(const float4*)&ucolsw[pb + 8];
            float4 uc3 = *(const float4*)&ucolsw[pb + 12];
            for (int o = g; o < NOPS + COLSN; o += 64) {
                const float* row = (o < NOPS) ? &op_emb[o * H + p * 16]
                                              : &col_emb[(o - NOPS) * H + p * 16];
                float4 e0 = *(const float4*)&row[0];
                float4 e1 = *(const float4*)&row[4];
                float4 e2 = *(const float4*)&row[8];
                float4 e3 = *(const float4*)&row[12];
                float s = (o < NOPS)
                    ? dot4(e0, uo0) + dot4(e1, uo1) + dot4(e2, uo2) + dot4(e3, uo3)
                    : dot4(e0, uc0) + dot4(e1, uc1) + dot4(e2, uc2) + dot4(e3, uc3);
                s = reduce16(s);
                if (p == 0) lgs[o] = s;
            }
        }
        __syncthreads();
        // softmaxes
        if (tid == 0) {
            float m = -1e30f;
            for (int k = 0; k < NOPS; ++k) m = fmaxf(m, lgs[k]);
            float e[NOPS], s = 0.f;
            for (int k = 0; k < NOPS; ++k) { e[k] = expf(lgs[k] - m); s += e[k]; }
            float inv = 1.f / s;
            for (int k = 0; k < NOPS; ++k) {
                float a = e[k] * inv;
                aop_s[k] = a;
                ws[WS_AOP + t * 16 + k] = a;
            }
        }
        if (tid >= 64 && tid < 128) {
            int lane = tid - 64;
            float v = lgs[NOPS + lane];
            float m = v;
            for (int off = 1; off < 64; off <<= 1) m = fmaxf(m, __shfl_xor(m, off));
            float e = expf(v - m);
            float s = e;
            for (int off = 1; off < 64; off <<= 1) s += __shfl_xor(s, off);
            float a = __fdividef(e, s);
            acol_s[lane] = a;
            ws[WS_ACOL + t * COLSN + lane] = a;
        }
        __syncthreads();
        // h-update: h = tanh(vhh + M_op^T a_op + M_col^T a_col)
        if (tid < H) {
            float s = vhh[tid];
            const float* mop = &ws[WS_MOP + tid];
            #pragma unroll
            for (int k = 0; k < NOPS; ++k) s += aop_s[k] * mop[k * H];
            const float* mcol = &ws[WS_MCOL + tid];
            #pragma unroll 8
            for (int c = 0; c < COLSN; ++c) s += acol_s[c] * mcol[c * H];
            hhsw[sw(tid)] = fast_tanh(s);
        }
        __syncthreads();
    }
}

// ==== table pass: LDS-staged coalesced loads, rs chain, lookup, reductions,
// ==== last block (atomic ticket) computes the scalar chain.
__global__ __launch_bounds__(256) void k_table(const float* __restrict__ table,
                                               float* __restrict__ ws,
                                               float* __restrict__ out) {
    __shared__ __attribute__((aligned(16))) float tile[4][64 * 68];  // 69.6 KB
    __shared__ float acol_l[4 * COLSN];
    __shared__ float aop_l[4 * 16];
    __shared__ float rs3[4][64];
    __shared__ float wred[4][8];
    int tid = threadIdx.x;
    int wid = tid >> 6;
    int lane = tid & 63;
    acol_l[tid] = ws[WS_ACOL + tid];
    if (tid < 64) aop_l[tid] = ws[WS_AOP + tid];
    float gp = ws[WS_PIV + 0];
    float lp = ws[WS_PIV + 1];

    long wv = (long)blockIdx.x * 4 + wid;
    long base = wv * 64;
    bool active = (base < ROWSN);

    if (active) {
        const float* src = table + base * COLSN;
        #pragma unroll
        for (int s = 0; s < 16; ++s) {
            float4 v = *(const float4*)(src + s * 256 + lane * 4);
            int row = s * 4 + (lane >> 4);
            int col = (lane & 15) * 4;
            *(float4*)&tile[wid][row * 68 + col] = v;
        }
    }
    __syncthreads();

    float cv[4] = {0,0,0,0}, gs[4] = {0,0,0,0}, ls[4] = {0,0,0,0};
    if (active) {
        const float* tr = &tile[wid][lane * 68];
        #pragma unroll
        for (int c4 = 0; c4 < 16; ++c4) {
            float4 v = *(const float4*)&tr[c4 * 4];
            float xs[4] = {v.x, v.y, v.z, v.w};
            #pragma unroll
            for (int e = 0; e < 4; ++e) {
                int c = c4 * 4 + e;
                float x = xs[e];
                float gt = (x > gp) ? 1.f : 0.f;
                float lt = (x < lp) ? 1.f : 0.f;
                #pragma unroll
                for (int t = 0; t < 4; ++t) {
                    float a = acol_l[t * COLSN + c];
                    cv[t] += x * a;
                    gs[t] += gt * a;
                    ls[t] += lt * a;
                }
            }
        }
    }
    float prev1 = 1.f, prev2 = 1.f;
    float dotp[4], cntp[4];
    #pragma unroll
    for (int t = 0; t < 4; ++t) {
        dotp[t] = active ? prev1 * cv[t] : 0.f;
        cntp[t] = active ? prev1 : 0.f;
        float cg = aop_l[t*16+3], cl = aop_l[t*16+4], cmn = aop_l[t*16+5];
        float cmx = aop_l[t*16+6], co = aop_l[t*16+8];
        float cid = aop_l[t*16+0] + aop_l[t*16+1] + aop_l[t*16+2] + aop_l[t*16+7];
        float rsn = cg * gs[t] + cl * ls[t] + cmn * fminf(prev1, prev2)
                  + cmx * fmaxf(prev1, prev2) + co + cid * prev1;
        prev2 = prev1; prev1 = rsn;
    }
    rs3[wid][lane] = prev1 * aop_l[3*16+7];
    __syncthreads();

    if (active) {
        float* dst = out + 1 + base * COLSN;
        #pragma unroll
        for (int s = 0; s < 16; ++s) {
            int row = s * 4 + (lane >> 4);
            int col = (lane & 15) * 4;
            float r3 = rs3[wid][row];
            float* o4 = dst + s * 256 + lane * 4;
            o4[0] = r3 * acol_l[3 * COLSN + col + 0];
            o4[1] = r3 * acol_l[3 * COLSN + col + 1];
            o4[2] = r3 * acol_l[3 * COLSN + col + 2];
            o4[3] = r3 * acol_l[3 * COLSN + col + 3];
        }
    }

    #pragma unroll
    for (int t = 0; t < 4; ++t) {
        float d = dotp[t], cn = cntp[t];
        for (int off = 1; off < 64; off <<= 1) { d += __shfl_xor(d, off); cn += __shfl_xor(cn, off); }
        if (lane == 0) { wred[wid][t] = d; wred[wid][4 + t] = cn; }
    }
    __syncthreads();
    if (tid < 8) {
        float s = wred[0][tid] + wred[1][tid] + wred[2][tid] + wred[3][tid];
        atomicAdd(&ws[WS_ACC + tid], s);
    }
    __syncthreads();

    if (tid == 0) {
        float old = atomicAdd(&ws[WS_TICKET], 1.0f);
        if ((int)(old + 0.5f) == NTBL_BLOCKS - 1) {
            float d0 = atomicAdd(&ws[WS_ACC+0], 0.f), d1 = atomicAdd(&ws[WS_ACC+1], 0.f);
            float d2 = atomicAdd(&ws[WS_ACC+2], 0.f), d3 = atomicAdd(&ws[WS_ACC+3], 0.f);
            float c0 = atomicAdd(&ws[WS_ACC+4], 0.f), c1 = atomicAdd(&ws[WS_ACC+5], 0.f);
            float c2 = atomicAdd(&ws[WS_ACC+6], 0.f), c3 = atomicAdd(&ws[WS_ACC+7], 0.f);
            const float* a0 = &aop_l[0];
            const float* a1 = &aop_l[16];
            const float* a2 = &aop_l[32];
            const float* a3 = &aop_l[48];
            float s0 = a0[0]*d0 + a0[1]*c0;
            float s1 = a1[0]*d1 + a1[1]*c1 + a1[2]*(0.f - s0);
            float s2 = a2[0]*d2 + a2[1]*c2 + a2[2]*(0.f - s1);
            float s3 = a3[0]*d3 + a3[1]*c3 + a3[2]*(s0 - s2);
            out[0] = s3;
        }
    }
}

extern "C" void kernel_launch(void* const* d_in, const int* in_sizes, int n_in,
                              void* d_out, int out_size, void* d_ws, size_t ws_size,
                              hipStream_t stream) {
    const int*   iq      = (const int*)  d_in[0];
    const float* qn      = (const float*)d_in[1];
    const int*   lwi     = (const int*)  d_in[2];
    const float* table   = (const float*)d_in[3];
    const float* E       = (const float*)d_in[4];
    const float* Wx      = (const float*)d_in[5];
    const float* Wh      = (const float*)d_in[6];
    const float* b       = (const float*)d_in[7];
    const float* W_op    = (const float*)d_in[8];
    const float* op_emb  = (const float*)d_in[9];
    const float* W_col   = (const float*)d_in[10];
    const float* col_emb = (const float*)d_in[11];
    const float* U       = (const float*)d_in[12];
    const float* W_hc    = (const float*)d_in[13];
    const float* W_hh    = (const float*)d_in[14];
    float* out = (float*)d_out;
    float* ws  = (float*)d_ws;

    hipLaunchKernelGGL(k_pre,  dim3(QLEN + 8), dim3(256), 0, stream,
                       iq, E, Wx, b, W_hc, op_emb, col_emb, ws);
    hipLaunchKernelGGL(k_main, dim3(1), dim3(1024), 0, stream,
                       Wh, lwi, U, qn, W_op, W_col, W_hh, op_emb, col_emb, ws);
    hipLaunchKernelGGL(k_table, dim3(NTBL_BLOCKS), dim3(256), 0, stream,
                       table, ws, out);
}